// Round 5
// baseline (12688.281 us; speedup 1.0000x reference)
//
#include <hip/hip_runtime.h>
#include <hip/hip_bf16.h>
#include <cstdint>

// ---------------------------------------------------------------------------
// LinearTransformer forward on MI355X.
// fp32 in/out (runtime-verified via detect_k); internal compute fp32.
// Encoder chunked 8x32 timesteps (ws ~7.5 MB); decoder sequential.
// FIX this round: feature map elu(x)+1 applies to BOTH q and k (ref lines
// `q = elu(q)+1; k = elu(k)+1`), previously applied to q only.
// ---------------------------------------------------------------------------

#define EP_NONE     0
#define EP_PE       1
#define EP_QKV_ENC  2
#define EP_RELU     3
#define EP_RES      4

__device__ __forceinline__ float bf2f(unsigned short s) {
    union { unsigned u; float f; } t; t.u = ((unsigned)s) << 16; return t.f;
}
__device__ __forceinline__ unsigned short f2bf(float f) {
    union { float f; unsigned u; } t; t.f = f;
    unsigned u = t.u;
    unsigned r = u + 0x7FFFu + ((u >> 16) & 1u);   // RNE
    return (unsigned short)(r >> 16);
}
__device__ __forceinline__ float ldS(const void* p, size_t i, bool b) {
    return b ? bf2f(((const unsigned short*)p)[i]) : ((const float*)p)[i];
}
__device__ __forceinline__ void ld4d(const void* p, size_t i, bool b, float o[4]) {
    if (b) {
        ushort4 v = *(const ushort4*)((const unsigned short*)p + i);
        o[0] = bf2f(v.x); o[1] = bf2f(v.y); o[2] = bf2f(v.z); o[3] = bf2f(v.w);
    } else {
        float4 v = *(const float4*)((const float*)p + i);
        o[0] = v.x; o[1] = v.y; o[2] = v.z; o[3] = v.w;
    }
}
__device__ __forceinline__ void stS(void* p, size_t i, bool b, float v) {
    if (b) ((unsigned short*)p)[i] = f2bf(v);
    else   ((float*)p)[i] = v;
}

// flag[0]=1 iff external tensors bf16; flag[1]=1 iff lengths int64.
__global__ void detect_k(const unsigned* __restrict__ ones,
                         const int* __restrict__ lens, int* __restrict__ flag)
{
    if (threadIdx.x == 0 && blockIdx.x == 0) {
        flag[0] = (ones[0] == 0x3F803F80u) ? 1 : 0;
        flag[1] = (lens[1] == 0 && lens[3] == 0) ? 1 : 0;
    }
}

// ---------------- tiled GEMM: C = A(M,K) @ W(N,K)^T + bias -----------------
// 64x64 tile, 256 thr, 4x4 acc. a_ext=1: A is external input x with chunk
// row-mapping arow = (r/32)*256 + t0 + (r%32).
template <int EPI>
__global__ __launch_bounds__(256) void gemm_k(
    const void* __restrict__ A, int a_ext, int t0,
    const void* __restrict__ W, size_t woff,
    const void* __restrict__ bias, size_t boff,
    const float* __restrict__ res, float* __restrict__ C,
    int M, int N, int K,
    const int* __restrict__ lengths, const int* __restrict__ flag)
{
    const bool ebf = flag[0] != 0;
    const bool abf = ebf && (a_ext != 0);
    __shared__ float Asm[16][64];
    __shared__ float Wsm[16][64];
    const int tid = threadIdx.x;
    const int tn = tid & 15, tm = tid >> 4;
    const int n0 = blockIdx.x * 64, m0 = blockIdx.y * 64;
    float acc[4][4] = {};

    const int lr = tid >> 2;           // 0..63 row-in-tile
    const int lc = (tid & 3) << 2;     // 0,4,8,12 k-in-ktile
    const int lrow = m0 + lr;          // chunk-local row
    const size_t arow = a_ext ? ((size_t)(lrow >> 5) * 256 + t0 + (lrow & 31))
                              : (size_t)lrow;
    const size_t abase = arow * K + lc;
    const size_t wbase = woff + (size_t)(n0 + lr) * K + lc;

    for (int k0 = 0; k0 < K; k0 += 16) {
        float av[4], wv[4];
        ld4d(A, abase + k0, abf, av);
        ld4d(W, wbase + k0, ebf, wv);
        Asm[lc + 0][lr] = av[0]; Asm[lc + 1][lr] = av[1];
        Asm[lc + 2][lr] = av[2]; Asm[lc + 3][lr] = av[3];
        Wsm[lc + 0][lr] = wv[0]; Wsm[lc + 1][lr] = wv[1];
        Wsm[lc + 2][lr] = wv[2]; Wsm[lc + 3][lr] = wv[3];
        __syncthreads();
#pragma unroll
        for (int kk = 0; kk < 16; ++kk) {
            float4 a4 = *(const float4*)&Asm[kk][tm << 2];
            float4 w4 = *(const float4*)&Wsm[kk][tn << 2];
            float ar[4] = {a4.x, a4.y, a4.z, a4.w};
            float wr[4] = {w4.x, w4.y, w4.z, w4.w};
#pragma unroll
            for (int i = 0; i < 4; ++i)
#pragma unroll
                for (int j = 0; j < 4; ++j)
                    acc[i][j] += ar[i] * wr[j];
        }
        __syncthreads();
    }

    const int row = m0 + (tm << 2);
    const int col = n0 + (tn << 2);
#pragma unroll
    for (int i = 0; i < 4; ++i) {
        int r = row + i;
        float vr[4];
#pragma unroll
        for (int j = 0; j < 4; ++j) {
            int c = col + j;
            float v = acc[i][j] + ldS(bias, boff + c, ebf);
            if constexpr (EPI == EP_PE) {
                int t = t0 + (r & 31);
                float freq = expf((float)(c & ~1) * (-9.210340371976184f / 1024.0f));
                float ang = (float)t * freq;
                v += (c & 1) ? cosf(ang) : sinf(ang);
            } else if constexpr (EPI == EP_QKV_ENC) {
                // feature map on BOTH q and k (ref: q=elu(q)+1; k=elu(k)+1)
                if (c < 2048)
                    v = v > 0.f ? v + 1.f : expf(v);
                // mask k and v for t >= length (applied after feature map)
                if (c >= 1024) {
                    int bb = r >> 5, t = t0 + (r & 31);
                    int len = lengths[flag[1] ? (bb << 1) : bb];
                    if (t >= len) v = 0.f;
                }
            } else if constexpr (EPI == EP_RELU) {
                v = fmaxf(v, 0.f);
            } else if constexpr (EPI == EP_RES) {
                v += res[(size_t)r * N + c];
            }
            vr[j] = v;
        }
        *(float4*)&C[(size_t)r * N + col] = *(float4*)vr;
    }
}

// ---------------- encoder linear attention, one 32-step chunk --------------
__global__ __launch_bounds__(64) void enc_attn_k(
    const float* __restrict__ qkvc, float* __restrict__ attnc,
    float* __restrict__ Sst, float* __restrict__ zst, int first)
{
    const int bid = blockIdx.x;
    const int mg = bid & 3, h = (bid >> 2) & 15, b = bid >> 6;
    const int bh = b * 16 + h;
    const int tid = threadIdx.x;
    const int ml = tid & 15, d4 = tid >> 4, db = d4 << 4;
    const int m = (mg << 4) + ml;

    float Sa[16], za[16];
    if (first) {
#pragma unroll
        for (int j = 0; j < 16; ++j) { Sa[j] = 0.f; za[j] = 0.f; }
    } else {
#pragma unroll
        for (int j = 0; j < 16; ++j) {
            Sa[j] = Sst[(size_t)bh * 4096 + (size_t)(db + j) * 64 + m];
            za[j] = zst[(size_t)bh * 64 + db + j];
        }
    }

    __shared__ float ks[32][64];
    __shared__ float qs[32][64];
    __shared__ float vs[32][16];

    for (int r = 0; r < 32; ++r) {
        const float* p = qkvc + (size_t)(b * 32 + r) * 3072 + (h << 6);
        qs[r][tid] = p[tid];
        ks[r][tid] = p[1024 + tid];
    }
    for (int i = tid; i < 512; i += 64) {
        int r = i >> 4, c = i & 15;
        vs[r][c] = qkvc[(size_t)(b * 32 + r) * 3072 + 2048 + (h << 6) + (mg << 4) + c];
    }
    __syncthreads();

    for (int tt = 0; tt < 32; ++tt) {
        float v = vs[tt][ml];
        const float4* k4 = (const float4*)&ks[tt][db];
        const float4* q4 = (const float4*)&qs[tt][db];
        float pn = 0.f, pd = 0.f;
#pragma unroll
        for (int j = 0; j < 4; ++j) {
            float4 kk = k4[j], qq = q4[j];
            Sa[4*j+0] += kk.x * v; za[4*j+0] += kk.x;
            Sa[4*j+1] += kk.y * v; za[4*j+1] += kk.y;
            Sa[4*j+2] += kk.z * v; za[4*j+2] += kk.z;
            Sa[4*j+3] += kk.w * v; za[4*j+3] += kk.w;
            pn += qq.x*Sa[4*j+0] + qq.y*Sa[4*j+1] + qq.z*Sa[4*j+2] + qq.w*Sa[4*j+3];
            pd += qq.x*za[4*j+0] + qq.y*za[4*j+1] + qq.z*za[4*j+2] + qq.w*za[4*j+3];
        }
        pn += __shfl_xor(pn, 16); pd += __shfl_xor(pd, 16);
        pn += __shfl_xor(pn, 32); pd += __shfl_xor(pd, 32);
        if (d4 == 0)
            attnc[(size_t)(b * 32 + tt) * 1024 + (h << 6) + m] = pn / (pd + 1e-6f);
    }

#pragma unroll
    for (int j = 0; j < 16; ++j)
        Sst[(size_t)bh * 4096 + (size_t)(db + j) * 64 + m] = Sa[j];
    if (ml == 0) {
#pragma unroll
        for (int j = 0; j < 16; ++j)
            zst[(size_t)bh * 64 + db + j] = za[j];
    }
}

// ---------------- layernorm, one block per token ---------------------------
__global__ __launch_bounds__(256) void ln_k(
    float* __restrict__ Y, const void* __restrict__ g, size_t goff,
    const void* __restrict__ b, size_t boff, const int* __restrict__ flag)
{
    const bool ebf = flag[0] != 0;
    __shared__ float red[256];
    const int row = blockIdx.x, tid = threadIdx.x;
    float4* y4 = (float4*)(Y + (size_t)row * 1024);
    float4 x = y4[tid];
    red[tid] = x.x + x.y + x.z + x.w;
    __syncthreads();
    for (int o = 128; o > 0; o >>= 1) {
        if (tid < o) red[tid] += red[tid + o];
        __syncthreads();
    }
    float mu = red[0] * (1.0f / 1024.0f);
    __syncthreads();
    float dx = x.x - mu, dy = x.y - mu, dz = x.z - mu, dw = x.w - mu;
    red[tid] = dx * dx + dy * dy + dz * dz + dw * dw;
    __syncthreads();
    for (int o = 128; o > 0; o >>= 1) {
        if (tid < o) red[tid] += red[tid + o];
        __syncthreads();
    }
    float rs = rsqrtf(red[0] * (1.0f / 1024.0f) + 1e-5f);
    float gv[4], bv[4];
    ld4d(g, goff + (size_t)tid * 4, ebf, gv);
    ld4d(b, boff + (size_t)tid * 4, ebf, bv);
    float4 o;
    o.x = dx * rs * gv[0] + bv[0];
    o.y = dy * rs * gv[1] + bv[1];
    o.z = dz * rs * gv[2] + bv[2];
    o.w = dw * rs * gv[3] + bv[3];
    y4[tid] = o;
}

// ---------------- skinny GEMM (M=4): 4 waves, wave->column n ---------------
template <int EPI, bool ODYN>
__global__ __launch_bounds__(256) void sgemm_k(
    const float* __restrict__ x, const void* __restrict__ W, size_t woff,
    const void* __restrict__ bias, size_t boff, const float* __restrict__ res,
    void* __restrict__ C, int N, int K, int ldc, int coff,
    const int* __restrict__ flag)
{
    const bool ebf = flag[0] != 0;
    const int n = blockIdx.x * 4 + (threadIdx.x >> 6);
    const int lane = threadIdx.x & 63;
    const size_t wbase = woff + (size_t)n * K;
    const float4* x0 = (const float4*)(x);
    const float4* x1 = (const float4*)(x + K);
    const float4* x2 = (const float4*)(x + 2 * K);
    const float4* x3 = (const float4*)(x + 3 * K);
    float a0 = 0.f, a1 = 0.f, a2 = 0.f, a3 = 0.f;
    const int nq = K >> 2;
    for (int i = lane; i < nq; i += 64) {
        float w[4];
        ld4d(W, wbase + (size_t)i * 4, ebf, w);
        float4 v;
        v = x0[i]; a0 += v.x * w[0] + v.y * w[1] + v.z * w[2] + v.w * w[3];
        v = x1[i]; a1 += v.x * w[0] + v.y * w[1] + v.z * w[2] + v.w * w[3];
        v = x2[i]; a2 += v.x * w[0] + v.y * w[1] + v.z * w[2] + v.w * w[3];
        v = x3[i]; a3 += v.x * w[0] + v.y * w[1] + v.z * w[2] + v.w * w[3];
    }
    for (int off = 32; off; off >>= 1) {
        a0 += __shfl_down(a0, off);
        a1 += __shfl_down(a1, off);
        a2 += __shfl_down(a2, off);
        a3 += __shfl_down(a3, off);
    }
    if (lane == 0) {
        float bn = ldS(bias, boff + n, ebf);
        float v[4] = {a0 + bn, a1 + bn, a2 + bn, a3 + bn};
#pragma unroll
        for (int bb = 0; bb < 4; ++bb) {
            if constexpr (EPI == EP_QKV_ENC) {   // dec qkv: elu+1 on q AND k
                if (n < 2048) v[bb] = v[bb] > 0.f ? v[bb] + 1.f : expf(v[bb]);
            } else if constexpr (EPI == EP_RELU) {
                v[bb] = fmaxf(v[bb], 0.f);
            } else if constexpr (EPI == EP_RES) {
                v[bb] += res[(size_t)bb * N + n];
            }
            size_t idx = (size_t)coff + (size_t)bb * ldc + n;
            if constexpr (ODYN) stS(C, idx, ebf, v[bb]);
            else                ((float*)C)[idx] = v[bb];
        }
    }
}

// ---------------- decoder attention step -----------------------------------
__global__ __launch_bounds__(64) void dec_attn_k(
    const float* __restrict__ qkv, float* __restrict__ Sst,
    float* __restrict__ zst, float* __restrict__ attn)
{
    const int bh = blockIdx.x;
    const int b = bh >> 4, h = bh & 15;
    const int lane = threadIdx.x;
    const float* base = qkv + (size_t)b * 3072 + (h << 6);
    float q = base[lane];
    float k = base[1024 + lane];
    float v = base[2048 + lane];
    __shared__ float kq[128];
    kq[lane] = k;
    kq[64 + lane] = q;
    float* zp = zst + (size_t)bh * 64;
    float zn = zp[lane] + k;
    zp[lane] = zn;
    float p = q * zn;
    for (int off = 32; off; off >>= 1) p += __shfl_xor(p, off);
    float den = p + 1e-6f;
    __syncthreads();
    float* Sp = Sst + (size_t)bh * 4096;
    float num = 0.f;
#pragma unroll 8
    for (int d = 0; d < 64; ++d) {
        float s = Sp[d * 64 + lane] + kq[d] * v;
        Sp[d * 64 + lane] = s;
        num += kq[64 + d] * s;
    }
    attn[(size_t)b * 1024 + (h << 6) + lane] = num / den;
}

// xd[b][e] = Xc[b*32+31][e]  (last timestep of final chunk)
__global__ __launch_bounds__(256) void copy_last_k(
    const float* __restrict__ Xc, float* __restrict__ xd)
{
    int i = blockIdx.x * 256 + threadIdx.x;     // 4096
    int b = i >> 10, e = i & 1023;
    xd[i] = Xc[(size_t)(b * 32 + 31) * 1024 + e];
}

// ===========================================================================
extern "C" void kernel_launch(void* const* d_in, const int* in_sizes, int n_in,
                              void* d_out, int out_size, void* d_ws, size_t ws_size,
                              hipStream_t stream)
{
    (void)n_in; (void)out_size; (void)ws_size;
    constexpr int E = 1024, B = 4, L = 4, TOUT = 32, NC = 1000;
    constexpr int CH = 32, NCH = 8, MC = B * CH;      // chunking

    const int o = (in_sizes[2] == 1) ? 0 : -1;        // scalar out_lengths?

    const void* x_in = d_in[0];
    const int*  lens = (const int*)d_in[1];
    const void* emb_w = d_in[3 + o];
    const void* emb_b = d_in[4 + o];
    const void* e_qkv_w = d_in[5 + o];  const void* e_qkv_b = d_in[6 + o];
    const void* e_out_w = d_in[7 + o];  const void* e_out_b = d_in[8 + o];
    const void* e_n1g = d_in[9 + o];    const void* e_n1b = d_in[10 + o];
    const void* e_n2g = d_in[11 + o];   const void* e_n2b = d_in[12 + o];
    const void* e_f1w = d_in[13 + o];   const void* e_f1b = d_in[14 + o];
    const void* e_f2w = d_in[15 + o];   const void* e_f2b = d_in[16 + o];
    const void* d_qkv_w = d_in[17 + o]; const void* d_qkv_b = d_in[18 + o];
    const void* d_out_w = d_in[19 + o]; const void* d_out_b = d_in[20 + o];
    const void* d_n1g = d_in[21 + o];   const void* d_n1b = d_in[22 + o];
    const void* d_n2g = d_in[23 + o];   const void* d_n2b = d_in[24 + o];
    const void* d_f1w = d_in[25 + o];   const void* d_f1b = d_in[26 + o];
    const void* d_f2w = d_in[27 + o];   const void* d_f2b = d_in[28 + o];
    const void* fc1_w = d_in[29 + o];   const void* fc1_b = d_in[30 + o];
    const void* fc2_w = d_in[31 + o];   const void* fc2_b = d_in[32 + o];

    // --- compact workspace layout (fp32), total ~7.6 MB ---
    float* wsf   = (float*)d_ws;
    int*   flag  = (int*)d_ws;                        // 64 floats
    float* xd    = wsf + 64;                          // 4096
    float* xd2   = xd + B * E;                        // 4096
    float* qkvd  = xd2 + B * E;                       // 12288
    float* attnd = qkvd + B * 3 * E;                  // 4096
    float* hfd   = attnd + B * E;                     // 4096
    float* Xc    = hfd + B * E;                       // MC*E = 131072
    float* Yc    = Xc + (size_t)MC * E;               // 131072
    float* attnc = Yc + (size_t)MC * E;               // 131072
    float* qkvc  = attnc + (size_t)MC * E;            // MC*3E = 393216
    float* zs    = qkvc + (size_t)MC * 3 * E;         // 16384
    float* Ss    = zs + (size_t)L * B * 16 * 64;      // 1048576
    float* Hc    = qkvc;                              // alias: qkvc dead after attn

    const size_t SstL = (size_t)B * 16 * 64 * 64;
    const size_t zstL = (size_t)B * 16 * 64;

    detect_k<<<1, 64, 0, stream>>>((const unsigned*)e_n1g, lens, flag);

    // ---- encoder: 8 chunks of 32 timesteps, layer loop inside chunk -------
    for (int c = 0; c < NCH; ++c) {
        const int t0 = c * CH;
        gemm_k<EP_PE><<<dim3(E / 64, MC / 64), 256, 0, stream>>>(
            x_in, 1, t0, emb_w, 0, emb_b, 0, nullptr, Xc,
            MC, E, 256, lens, flag);

        for (int l = 0; l < L; ++l) {
            const size_t qw_o = (size_t)l * 3 * E * E, qb_o = (size_t)l * 3 * E;
            const size_t ow_o = (size_t)l * E * E,     ob_o = (size_t)l * E;
            const size_t fw_o = (size_t)l * E * E,     fb_o = (size_t)l * E;
            const size_t g_o  = (size_t)l * E;

            gemm_k<EP_QKV_ENC><<<dim3(3 * E / 64, MC / 64), 256, 0, stream>>>(
                Xc, 0, t0, e_qkv_w, qw_o, e_qkv_b, qb_o, nullptr, qkvc,
                MC, 3 * E, E, lens, flag);
            enc_attn_k<<<B * 16 * 4, 64, 0, stream>>>(
                qkvc, attnc, Ss + l * SstL, zs + l * zstL, c == 0 ? 1 : 0);
            gemm_k<EP_RES><<<dim3(E / 64, MC / 64), 256, 0, stream>>>(
                attnc, 0, t0, e_out_w, ow_o, e_out_b, ob_o, Xc, Yc,
                MC, E, E, lens, flag);
            ln_k<<<MC, 256, 0, stream>>>(Yc, e_n1g, g_o, e_n1b, g_o, flag);
            gemm_k<EP_RELU><<<dim3(E / 64, MC / 64), 256, 0, stream>>>(
                Yc, 0, t0, e_f1w, fw_o, e_f1b, fb_o, nullptr, Hc,
                MC, E, E, lens, flag);
            gemm_k<EP_RES><<<dim3(E / 64, MC / 64), 256, 0, stream>>>(
                Hc, 0, t0, e_f2w, fw_o, e_f2b, fb_o, Yc, Xc,
                MC, E, E, lens, flag);
            ln_k<<<MC, 256, 0, stream>>>(Xc, e_n2g, g_o, e_n2b, g_o, flag);
        }
    }

    copy_last_k<<<16, 256, 0, stream>>>(Xc, xd);

    // ---- decoder: 32 sequential steps -------------------------------------
    for (int t = 0; t < TOUT; ++t) {
        for (int l = 0; l < L; ++l) {
            const size_t qw_o = (size_t)l * 3 * E * E, qb_o = (size_t)l * 3 * E;
            const size_t ow_o = (size_t)l * E * E,     ob_o = (size_t)l * E;
            const size_t fw_o = (size_t)l * E * E,     fb_o = (size_t)l * E;
            const size_t g_o  = (size_t)l * E;

            sgemm_k<EP_QKV_ENC, false><<<3 * E / 4, 256, 0, stream>>>(
                xd, d_qkv_w, qw_o, d_qkv_b, qb_o, nullptr, qkvd,
                3 * E, E, 3 * E, 0, flag);
            dec_attn_k<<<B * 16, 64, 0, stream>>>(
                qkvd, Ss + l * SstL, zs + l * zstL, attnd);
            sgemm_k<EP_RES, false><<<E / 4, 256, 0, stream>>>(
                attnd, d_out_w, ow_o, d_out_b, ob_o, xd, xd2,
                E, E, E, 0, flag);
            ln_k<<<B, 256, 0, stream>>>(xd2, d_n1g, g_o, d_n1b, g_o, flag);
            sgemm_k<EP_RELU, false><<<E / 4, 256, 0, stream>>>(
                xd2, d_f1w, fw_o, d_f1b, fb_o, nullptr, hfd,
                E, E, E, 0, flag);
            sgemm_k<EP_RES, false><<<E / 4, 256, 0, stream>>>(
                hfd, d_f2w, fw_o, d_f2b, fb_o, xd2, xd,
                E, E, E, 0, flag);
            ln_k<<<B, 256, 0, stream>>>(xd, d_n2g, g_o, d_n2b, g_o, flag);
        }
        sgemm_k<EP_RELU, false><<<E / 4, 256, 0, stream>>>(
            xd, fc1_w, 0, fc1_b, 0, nullptr, hfd, E, E, E, 0, flag);
        sgemm_k<EP_NONE, true><<<NC / 4, 256, 0, stream>>>(
            hfd, fc2_w, 0, fc2_b, 0, nullptr, d_out,
            NC, E, TOUT * NC, t * NC, flag);
    }
}

// Round 6
// 6154.721 us; speedup vs baseline: 2.0616x; 2.0616x over previous
//
#include <hip/hip_runtime.h>
#include <hip/hip_bf16.h>
#include <cstdint>

// ---------------------------------------------------------------------------
// LinearTransformer forward on MI355X.  fp32 compute throughout.
// R6: (a) encoder un-chunked (full-seq M=1024 GEMMs) when ws_size >= 30 MiB,
//     runtime-gated host-side (constant per run -> graph-safe);
//     (b) decoder LayerNorms fused into sgemms via block-local stats
//     recompute (kernels/step 30 -> 22, no 4-block ln_k launches).
// ---------------------------------------------------------------------------

#define EP_NONE     0
#define EP_PE       1
#define EP_QKV      2
#define EP_RELU     3
#define EP_RES      4

__device__ __forceinline__ float bf2f(unsigned short s) {
    union { unsigned u; float f; } t; t.u = ((unsigned)s) << 16; return t.f;
}
__device__ __forceinline__ unsigned short f2bf(float f) {
    union { float f; unsigned u; } t; t.f = f;
    unsigned u = t.u;
    unsigned r = u + 0x7FFFu + ((u >> 16) & 1u);   // RNE
    return (unsigned short)(r >> 16);
}
__device__ __forceinline__ float ldS(const void* p, size_t i, bool b) {
    return b ? bf2f(((const unsigned short*)p)[i]) : ((const float*)p)[i];
}
__device__ __forceinline__ void ld4d(const void* p, size_t i, bool b, float o[4]) {
    if (b) {
        ushort4 v = *(const ushort4*)((const unsigned short*)p + i);
        o[0] = bf2f(v.x); o[1] = bf2f(v.y); o[2] = bf2f(v.z); o[3] = bf2f(v.w);
    } else {
        float4 v = *(const float4*)((const float*)p + i);
        o[0] = v.x; o[1] = v.y; o[2] = v.z; o[3] = v.w;
    }
}
__device__ __forceinline__ void stS(void* p, size_t i, bool b, float v) {
    if (b) ((unsigned short*)p)[i] = f2bf(v);
    else   ((float*)p)[i] = v;
}

// flag[0]=1 iff external tensors bf16; flag[1]=1 iff lengths int64.
__global__ void detect_k(const unsigned* __restrict__ ones,
                         const int* __restrict__ lens, int* __restrict__ flag)
{
    if (threadIdx.x == 0 && blockIdx.x == 0) {
        flag[0] = (ones[0] == 0x3F803F80u) ? 1 : 0;
        flag[1] = (lens[1] == 0 && lens[3] == 0) ? 1 : 0;
    }
}

// ---------------- tiled GEMM: C = A(M,K) @ W(N,K)^T + bias -----------------
// 64x64 tile, 256 thr, 4x4 acc.  a_ext=1: A is external x with chunk row-map
// arow = (lrow>>chb)*256 + t0 + (lrow & ((1<<chb)-1)).  chb=8 => identity.
template <int EPI>
__global__ __launch_bounds__(256) void gemm_k(
    const void* __restrict__ A, int a_ext, int t0, int chb,
    const void* __restrict__ W, size_t woff,
    const void* __restrict__ bias, size_t boff,
    const float* __restrict__ res, float* __restrict__ C,
    int M, int N, int K,
    const int* __restrict__ lengths, const int* __restrict__ flag)
{
    const bool ebf = flag[0] != 0;
    const bool abf = ebf && (a_ext != 0);
    __shared__ float Asm[16][64];
    __shared__ float Wsm[16][64];
    const int tid = threadIdx.x;
    const int tn = tid & 15, tm = tid >> 4;
    const int n0 = blockIdx.x * 64, m0 = blockIdx.y * 64;
    const int chm = (1 << chb) - 1;
    float acc[4][4] = {};

    const int lr = tid >> 2;
    const int lc = (tid & 3) << 2;
    const int lrow = m0 + lr;
    const size_t arow = a_ext ? ((size_t)(lrow >> chb) * 256 + t0 + (lrow & chm))
                              : (size_t)lrow;
    const size_t abase = arow * K + lc;
    const size_t wbase = woff + (size_t)(n0 + lr) * K + lc;

    for (int k0 = 0; k0 < K; k0 += 16) {
        float av[4], wv[4];
        ld4d(A, abase + k0, abf, av);
        ld4d(W, wbase + k0, ebf, wv);
        Asm[lc + 0][lr] = av[0]; Asm[lc + 1][lr] = av[1];
        Asm[lc + 2][lr] = av[2]; Asm[lc + 3][lr] = av[3];
        Wsm[lc + 0][lr] = wv[0]; Wsm[lc + 1][lr] = wv[1];
        Wsm[lc + 2][lr] = wv[2]; Wsm[lc + 3][lr] = wv[3];
        __syncthreads();
#pragma unroll
        for (int kk = 0; kk < 16; ++kk) {
            float4 a4 = *(const float4*)&Asm[kk][tm << 2];
            float4 w4 = *(const float4*)&Wsm[kk][tn << 2];
            float ar[4] = {a4.x, a4.y, a4.z, a4.w};
            float wr[4] = {w4.x, w4.y, w4.z, w4.w};
#pragma unroll
            for (int i = 0; i < 4; ++i)
#pragma unroll
                for (int j = 0; j < 4; ++j)
                    acc[i][j] += ar[i] * wr[j];
        }
        __syncthreads();
    }

    const int row = m0 + (tm << 2);
    const int col = n0 + (tn << 2);
#pragma unroll
    for (int i = 0; i < 4; ++i) {
        int r = row + i;
        float vr[4];
#pragma unroll
        for (int j = 0; j < 4; ++j) {
            int c = col + j;
            float v = acc[i][j] + ldS(bias, boff + c, ebf);
            if constexpr (EPI == EP_PE) {
                int t = t0 + (r & chm);
                float freq = expf((float)(c & ~1) * (-9.210340371976184f / 1024.0f));
                float ang = (float)t * freq;
                v += (c & 1) ? cosf(ang) : sinf(ang);
            } else if constexpr (EPI == EP_QKV) {
                if (c < 2048)
                    v = v > 0.f ? v + 1.f : expf(v);   // elu(q)+1 AND elu(k)+1
                if (c >= 1024) {
                    int bb = r >> chb, t = t0 + (r & chm);
                    int len = lengths[flag[1] ? (bb << 1) : bb];
                    if (t >= len) v = 0.f;             // mask k,v
                }
            } else if constexpr (EPI == EP_RELU) {
                v = fmaxf(v, 0.f);
            } else if constexpr (EPI == EP_RES) {
                v += res[(size_t)r * N + c];
            }
            vr[j] = v;
        }
        *(float4*)&C[(size_t)r * N + col] = *(float4*)vr;
    }
}

// ---------------- encoder linear attention over one chunk of CH steps ------
// grid B*H*4 (4 col-groups of 16 per (b,h)), 64 thr; 32-step LDS subtiles.
__global__ __launch_bounds__(64) void enc_attn_k(
    const float* __restrict__ qkvc, float* __restrict__ attnc,
    float* __restrict__ Sst, float* __restrict__ zst, int first, int CH)
{
    const int bid = blockIdx.x;
    const int mg = bid & 3, h = (bid >> 2) & 15, b = bid >> 6;
    const int bh = b * 16 + h;
    const int tid = threadIdx.x;
    const int ml = tid & 15, d4 = tid >> 4, db = d4 << 4;
    const int m = (mg << 4) + ml;

    float Sa[16], za[16];
    if (first) {
#pragma unroll
        for (int j = 0; j < 16; ++j) { Sa[j] = 0.f; za[j] = 0.f; }
    } else {
#pragma unroll
        for (int j = 0; j < 16; ++j) {
            Sa[j] = Sst[(size_t)bh * 4096 + (size_t)(db + j) * 64 + m];
            za[j] = zst[(size_t)bh * 64 + db + j];
        }
    }

    __shared__ float ks[32][64];
    __shared__ float qs[32][64];
    __shared__ float vs[32][16];

    for (int s = 0; s < CH; s += 32) {
        __syncthreads();
        for (int r = 0; r < 32; ++r) {
            const float* p = qkvc + (size_t)(b * CH + s + r) * 3072 + (h << 6);
            qs[r][tid] = p[tid];
            ks[r][tid] = p[1024 + tid];
        }
        for (int i = tid; i < 512; i += 64) {
            int r = i >> 4, c = i & 15;
            vs[r][c] = qkvc[(size_t)(b * CH + s + r) * 3072 + 2048 + (h << 6) + (mg << 4) + c];
        }
        __syncthreads();

        for (int tt = 0; tt < 32; ++tt) {
            float v = vs[tt][ml];
            const float4* k4 = (const float4*)&ks[tt][db];
            const float4* q4 = (const float4*)&qs[tt][db];
            float pn = 0.f, pd = 0.f;
#pragma unroll
            for (int j = 0; j < 4; ++j) {
                float4 kk = k4[j], qq = q4[j];
                Sa[4*j+0] += kk.x * v; za[4*j+0] += kk.x;
                Sa[4*j+1] += kk.y * v; za[4*j+1] += kk.y;
                Sa[4*j+2] += kk.z * v; za[4*j+2] += kk.z;
                Sa[4*j+3] += kk.w * v; za[4*j+3] += kk.w;
                pn += qq.x*Sa[4*j+0] + qq.y*Sa[4*j+1] + qq.z*Sa[4*j+2] + qq.w*Sa[4*j+3];
                pd += qq.x*za[4*j+0] + qq.y*za[4*j+1] + qq.z*za[4*j+2] + qq.w*za[4*j+3];
            }
            pn += __shfl_xor(pn, 16); pd += __shfl_xor(pd, 16);
            pn += __shfl_xor(pn, 32); pd += __shfl_xor(pd, 32);
            if (d4 == 0)
                attnc[(size_t)(b * CH + s + tt) * 1024 + (h << 6) + m] = pn / (pd + 1e-6f);
        }
    }

#pragma unroll
    for (int j = 0; j < 16; ++j)
        Sst[(size_t)bh * 4096 + (size_t)(db + j) * 64 + m] = Sa[j];
    if (ml == 0) {
#pragma unroll
        for (int j = 0; j < 16; ++j)
            zst[(size_t)bh * 64 + db + j] = za[j];
    }
}

// ---------------- layernorm (encoder only), one block per token ------------
__global__ __launch_bounds__(256) void ln_k(
    float* __restrict__ Y, const void* __restrict__ g, size_t goff,
    const void* __restrict__ b, size_t boff, const int* __restrict__ flag)
{
    const bool ebf = flag[0] != 0;
    __shared__ float red[256];
    const int row = blockIdx.x, tid = threadIdx.x;
    float4* y4 = (float4*)(Y + (size_t)row * 1024);
    float4 x = y4[tid];
    red[tid] = x.x + x.y + x.z + x.w;
    __syncthreads();
    for (int o = 128; o > 0; o >>= 1) {
        if (tid < o) red[tid] += red[tid + o];
        __syncthreads();
    }
    float mu = red[0] * (1.0f / 1024.0f);
    __syncthreads();
    float dx = x.x - mu, dy = x.y - mu, dz = x.z - mu, dw = x.w - mu;
    red[tid] = dx * dx + dy * dy + dz * dz + dw * dw;
    __syncthreads();
    for (int o = 128; o > 0; o >>= 1) {
        if (tid < o) red[tid] += red[tid + o];
        __syncthreads();
    }
    float rs = rsqrtf(red[0] * (1.0f / 1024.0f) + 1e-5f);
    float gv[4], bv[4];
    ld4d(g, goff + (size_t)tid * 4, ebf, gv);
    ld4d(b, boff + (size_t)tid * 4, ebf, bv);
    float4 o;
    o.x = dx * rs * gv[0] + bv[0];
    o.y = dy * rs * gv[1] + bv[1];
    o.z = dz * rs * gv[2] + bv[2];
    o.w = dw * rs * gv[3] + bv[3];
    y4[tid] = o;
}

// ---------------- decoder skinny GEMM (M=4) with fused LayerNorm -----------
// XN: dot-input x is normalized on the fly: xn = (x-mu)*rs*g + b, stats
//     computed block-locally (wave w reduces row w).
// RES: 0 none; 1 add res raw; 2 add LN(res) (stats over res rows).
template <int EPI, bool XN, int RES, bool ODYN>
__global__ __launch_bounds__(256) void sgemm2_k(
    const float* __restrict__ x,
    const void* __restrict__ lxg, size_t lxgo,
    const void* __restrict__ lxb, size_t lxbo,
    const float* __restrict__ res,
    const void* __restrict__ lrg, size_t lrgo,
    const void* __restrict__ lrb, size_t lrbo,
    const void* __restrict__ W, size_t woff,
    const void* __restrict__ bias, size_t boff,
    void* __restrict__ C, int N, int K, int ldc, int coff,
    const int* __restrict__ flag)
{
    const bool ebf = flag[0] != 0;
    const int wv = threadIdx.x >> 6, lane = threadIdx.x & 63;
    __shared__ float sxm[4], sxr[4], srm[4], srr[4];

    if (XN) {
        const float4* xr = (const float4*)(x + (size_t)wv * K);
        float s = 0.f, q = 0.f;
        for (int i = lane; i < (K >> 2); i += 64) {
            float4 v = xr[i];
            s += v.x + v.y + v.z + v.w;
            q += v.x*v.x + v.y*v.y + v.z*v.z + v.w*v.w;
        }
        for (int o2 = 32; o2; o2 >>= 1) { s += __shfl_xor(s, o2); q += __shfl_xor(q, o2); }
        if (lane == 0) {
            float mu = s / (float)K;
            sxm[wv] = mu;
            sxr[wv] = rsqrtf(q / (float)K - mu * mu + 1e-5f);
        }
    }
    if (RES == 2) {
        const float4* rr = (const float4*)(res + (size_t)wv * N);
        float s = 0.f, q = 0.f;
        for (int i = lane; i < (N >> 2); i += 64) {
            float4 v = rr[i];
            s += v.x + v.y + v.z + v.w;
            q += v.x*v.x + v.y*v.y + v.z*v.z + v.w*v.w;
        }
        for (int o2 = 32; o2; o2 >>= 1) { s += __shfl_xor(s, o2); q += __shfl_xor(q, o2); }
        if (lane == 0) {
            float mu = s / (float)N;
            srm[wv] = mu;
            srr[wv] = rsqrtf(q / (float)N - mu * mu + 1e-5f);
        }
    }
    if (XN || RES == 2) __syncthreads();

    const int n = blockIdx.x * 4 + wv;
    const size_t wbase = woff + (size_t)n * K;
    const float4* x0 = (const float4*)(x);
    const float4* x1 = (const float4*)(x + K);
    const float4* x2 = (const float4*)(x + 2 * K);
    const float4* x3 = (const float4*)(x + 3 * K);
    float m0=0,r0=1,m1=0,r1=1,m2=0,r2=1,m3=0,r3=1;
    if (XN) {
        m0 = sxm[0]; r0 = sxr[0]; m1 = sxm[1]; r1 = sxr[1];
        m2 = sxm[2]; r2 = sxr[2]; m3 = sxm[3]; r3 = sxr[3];
    }
    float a0 = 0.f, a1 = 0.f, a2 = 0.f, a3 = 0.f;
    for (int i = lane; i < (K >> 2); i += 64) {
        float w[4];
        ld4d(W, wbase + (size_t)i * 4, ebf, w);
        float g[4], be[4];
        if (XN) {
            ld4d(lxg, lxgo + (size_t)i * 4, ebf, g);
            ld4d(lxb, lxbo + (size_t)i * 4, ebf, be);
        }
        float4 v;
#define ROWACC(XP, ACC, MU, RS)                                               \
        v = XP[i];                                                            \
        if (XN) {                                                             \
            ACC += ((v.x - MU) * RS * g[0] + be[0]) * w[0]                    \
                 + ((v.y - MU) * RS * g[1] + be[1]) * w[1]                    \
                 + ((v.z - MU) * RS * g[2] + be[2]) * w[2]                    \
                 + ((v.w - MU) * RS * g[3] + be[3]) * w[3];                   \
        } else {                                                              \
            ACC += v.x * w[0] + v.y * w[1] + v.z * w[2] + v.w * w[3];         \
        }
        ROWACC(x0, a0, m0, r0)
        ROWACC(x1, a1, m1, r1)
        ROWACC(x2, a2, m2, r2)
        ROWACC(x3, a3, m3, r3)
#undef ROWACC
    }
    for (int o2 = 32; o2; o2 >>= 1) {
        a0 += __shfl_down(a0, o2);
        a1 += __shfl_down(a1, o2);
        a2 += __shfl_down(a2, o2);
        a3 += __shfl_down(a3, o2);
    }
    if (lane == 0) {
        float bn = ldS(bias, boff + n, ebf);
        float v[4] = {a0 + bn, a1 + bn, a2 + bn, a3 + bn};
        float rg = 0.f, rb = 0.f;
        if (RES == 2) { rg = ldS(lrg, lrgo + n, ebf); rb = ldS(lrb, lrbo + n, ebf); }
#pragma unroll
        for (int b2 = 0; b2 < 4; ++b2) {
            if constexpr (RES == 1) {
                v[b2] += res[(size_t)b2 * N + n];
            } else if constexpr (RES == 2) {
                v[b2] += (res[(size_t)b2 * N + n] - srm[b2]) * srr[b2] * rg + rb;
            }
            if constexpr (EPI == EP_QKV) {
                if (n < 2048) v[b2] = v[b2] > 0.f ? v[b2] + 1.f : expf(v[b2]);
            } else if constexpr (EPI == EP_RELU) {
                v[b2] = fmaxf(v[b2], 0.f);
            }
            size_t idx = (size_t)coff + (size_t)b2 * ldc + n;
            if constexpr (ODYN) stS(C, idx, ebf, v[b2]);
            else                ((float*)C)[idx] = v[b2];
        }
    }
}

// ---------------- decoder attention step -----------------------------------
__global__ __launch_bounds__(64) void dec_attn_k(
    const float* __restrict__ qkv, float* __restrict__ Sst,
    float* __restrict__ zst, float* __restrict__ attn)
{
    const int bh = blockIdx.x;
    const int b = bh >> 4, h = bh & 15;
    const int lane = threadIdx.x;
    const float* base = qkv + (size_t)b * 3072 + (h << 6);
    float q = base[lane];
    float k = base[1024 + lane];
    float v = base[2048 + lane];
    __shared__ float kq[128];
    kq[lane] = k;
    kq[64 + lane] = q;
    float* zp = zst + (size_t)bh * 64;
    float zn = zp[lane] + k;
    zp[lane] = zn;
    float p = q * zn;
    for (int off = 32; off; off >>= 1) p += __shfl_xor(p, off);
    float den = p + 1e-6f;
    __syncthreads();
    float* Sp = Sst + (size_t)bh * 4096;
    float num = 0.f;
#pragma unroll 8
    for (int d = 0; d < 64; ++d) {
        float s = Sp[d * 64 + lane] + kq[d] * v;
        Sp[d * 64 + lane] = s;
        num += kq[64 + d] * s;
    }
    attn[(size_t)b * 1024 + (h << 6) + lane] = num / den;
}

// xd[b][e] = Xc[(b*CH + CH-1)][e]
__global__ __launch_bounds__(256) void copy_last_k(
    const float* __restrict__ Xc, float* __restrict__ xd, int CH)
{
    int i = blockIdx.x * 256 + threadIdx.x;     // 4096
    int b = i >> 10, e = i & 1023;
    xd[i] = Xc[(size_t)(b * CH + CH - 1) * 1024 + e];
}

// ===========================================================================
extern "C" void kernel_launch(void* const* d_in, const int* in_sizes, int n_in,
                              void* d_out, int out_size, void* d_ws, size_t ws_size,
                              hipStream_t stream)
{
    (void)n_in; (void)out_size;
    constexpr int E = 1024, B = 4, L = 4, TOUT = 32, NC = 1000;

    // encoder chunking: full sequence if workspace allows (~29.6 MB needed)
    const int CH  = (ws_size >= (size_t)30 * 1024 * 1024) ? 256 : 32;
    const int chb = (CH == 256) ? 8 : 5;
    const int NCH = 256 / CH;
    const int MC  = B * CH;

    const int o = (in_sizes[2] == 1) ? 0 : -1;        // scalar out_lengths?

    const void* x_in = d_in[0];
    const int*  lens = (const int*)d_in[1];
    const void* emb_w = d_in[3 + o];
    const void* emb_b = d_in[4 + o];
    const void* e_qkv_w = d_in[5 + o];  const void* e_qkv_b = d_in[6 + o];
    const void* e_out_w = d_in[7 + o];  const void* e_out_b = d_in[8 + o];
    const void* e_n1g = d_in[9 + o];    const void* e_n1b = d_in[10 + o];
    const void* e_n2g = d_in[11 + o];   const void* e_n2b = d_in[12 + o];
    const void* e_f1w = d_in[13 + o];   const void* e_f1b = d_in[14 + o];
    const void* e_f2w = d_in[15 + o];   const void* e_f2b = d_in[16 + o];
    const void* d_qkv_w = d_in[17 + o]; const void* d_qkv_b = d_in[18 + o];
    const void* d_out_w = d_in[19 + o]; const void* d_out_b = d_in[20 + o];
    const void* d_n1g = d_in[21 + o];   const void* d_n1b = d_in[22 + o];
    const void* d_n2g = d_in[23 + o];   const void* d_n2b = d_in[24 + o];
    const void* d_f1w = d_in[25 + o];   const void* d_f1b = d_in[26 + o];
    const void* d_f2w = d_in[27 + o];   const void* d_f2b = d_in[28 + o];
    const void* fc1_w = d_in[29 + o];   const void* fc1_b = d_in[30 + o];
    const void* fc2_w = d_in[31 + o];   const void* fc2_b = d_in[32 + o];

    // ---- workspace layout (fp32) ------------------------------------------
    float* wsf   = (float*)d_ws;
    int*   flag  = (int*)d_ws;                        // 64 floats
    float* u     = wsf + 64;                          // 4096 (xd / pre-LN2)
    float* t1    = u + B * E;                         // 4096 (pre-LN1)
    float* qkvd  = t1 + B * E;                        // 12288
    float* attnd = qkvd + B * 3 * E;                  // 4096
    float* hfd   = attnd + B * E;                     // 4096
    float* Xc    = hfd + B * E;                       // MC*E
    float* Yc    = Xc + (size_t)MC * E;               // MC*E
    float* attnc = Yc + (size_t)MC * E;               // MC*E
    float* qkvc  = attnc + (size_t)MC * E;            // MC*3E
    float* zs    = qkvc + (size_t)MC * 3 * E;         // 16384
    float* Ss    = zs + (size_t)L * B * 16 * 64;      // 1048576
    float* Hc    = qkvc;                              // alias (qkvc dead after attn)

    const size_t SstL = (size_t)B * 16 * 64 * 64;
    const size_t zstL = (size_t)B * 16 * 64;

    detect_k<<<1, 64, 0, stream>>>((const unsigned*)e_n1g, lens, flag);

    // ---- encoder ----------------------------------------------------------
    for (int c = 0; c < NCH; ++c) {
        const int t0 = c * CH;
        gemm_k<EP_PE><<<dim3(E / 64, MC / 64), 256, 0, stream>>>(
            x_in, 1, t0, chb, emb_w, 0, emb_b, 0, nullptr, Xc,
            MC, E, 256, lens, flag);

        for (int l = 0; l < L; ++l) {
            const size_t qw_o = (size_t)l * 3 * E * E, qb_o = (size_t)l * 3 * E;
            const size_t ow_o = (size_t)l * E * E,     ob_o = (size_t)l * E;
            const size_t fw_o = (size_t)l * E * E,     fb_o = (size_t)l * E;
            const size_t g_o  = (size_t)l * E;

            gemm_k<EP_QKV><<<dim3(3 * E / 64, MC / 64), 256, 0, stream>>>(
                Xc, 0, t0, chb, e_qkv_w, qw_o, e_qkv_b, qb_o, nullptr, qkvc,
                MC, 3 * E, E, lens, flag);
            enc_attn_k<<<B * 16 * 4, 64, 0, stream>>>(
                qkvc, attnc, Ss + l * SstL, zs + l * zstL, c == 0 ? 1 : 0, CH);
            gemm_k<EP_RES><<<dim3(E / 64, MC / 64), 256, 0, stream>>>(
                attnc, 0, t0, chb, e_out_w, ow_o, e_out_b, ob_o, Xc, Yc,
                MC, E, E, lens, flag);
            ln_k<<<MC, 256, 0, stream>>>(Yc, e_n1g, g_o, e_n1b, g_o, flag);
            gemm_k<EP_RELU><<<dim3(E / 64, MC / 64), 256, 0, stream>>>(
                Yc, 0, t0, chb, e_f1w, fw_o, e_f1b, fb_o, nullptr, Hc,
                MC, E, E, lens, flag);
            gemm_k<EP_RES><<<dim3(E / 64, MC / 64), 256, 0, stream>>>(
                Hc, 0, t0, chb, e_f2w, fw_o, e_f2b, fb_o, Yc, Xc,
                MC, E, E, lens, flag);
            ln_k<<<MC, 256, 0, stream>>>(Xc, e_n2g, g_o, e_n2b, g_o, flag);
        }
    }

    copy_last_k<<<16, 256, 0, stream>>>(Xc, u, CH);

    // ---- decoder: 32 sequential steps, LN fused into sgemms ---------------
    for (int t = 0; t < TOUT; ++t) {
        for (int l = 0; l < L; ++l) {
            const size_t qw_o = (size_t)l * 3 * E * E, qb_o = (size_t)l * 3 * E;
            const size_t ow_o = (size_t)l * E * E,     ob_o = (size_t)l * E;
            const size_t fw_o = (size_t)l * E * E,     fb_o = (size_t)l * E;
            const size_t g_o  = (size_t)l * E;
            const size_t pg_o = (size_t)((l == 0) ? 3 : (l - 1)) * E; // prev LN2

            // K1: qkvd = phi( [LN2(u)] @ qkv_w^T + qkv_b )
            if (t == 0 && l == 0)
                sgemm2_k<EP_QKV, false, 0, false><<<3 * E / 4, 256, 0, stream>>>(
                    u, nullptr, 0, nullptr, 0, nullptr, nullptr, 0, nullptr, 0,
                    d_qkv_w, qw_o, d_qkv_b, qb_o, qkvd, 3 * E, E, 3 * E, 0, flag);
            else
                sgemm2_k<EP_QKV, true, 0, false><<<3 * E / 4, 256, 0, stream>>>(
                    u, d_n2g, pg_o, d_n2b, pg_o, nullptr, nullptr, 0, nullptr, 0,
                    d_qkv_w, qw_o, d_qkv_b, qb_o, qkvd, 3 * E, E, 3 * E, 0, flag);

            // K2: attention state update
            dec_attn_k<<<B * 16, 64, 0, stream>>>(
                qkvd, Ss + l * SstL, zs + l * zstL, attnd);

            // K3: t1 = attnd @ out_w^T + out_b + [LN2(u) | u raw at t0l0]
            if (t == 0 && l == 0)
                sgemm2_k<EP_NONE, false, 1, false><<<E / 4, 256, 0, stream>>>(
                    attnd, nullptr, 0, nullptr, 0, u, nullptr, 0, nullptr, 0,
                    d_out_w, ow_o, d_out_b, ob_o, t1, E, E, E, 0, flag);
            else
                sgemm2_k<EP_NONE, false, 2, false><<<E / 4, 256, 0, stream>>>(
                    attnd, nullptr, 0, nullptr, 0, u, d_n2g, pg_o, d_n2b, pg_o,
                    d_out_w, ow_o, d_out_b, ob_o, t1, E, E, E, 0, flag);

            // K4: hfd = relu( LN1(t1) @ f1w^T + f1b )
            sgemm2_k<EP_RELU, true, 0, false><<<E / 4, 256, 0, stream>>>(
                t1, d_n1g, g_o, d_n1b, g_o, nullptr, nullptr, 0, nullptr, 0,
                d_f1w, fw_o, d_f1b, fb_o, hfd, E, E, E, 0, flag);

            // K5: u = hfd @ f2w^T + f2b + LN1(t1)
            sgemm2_k<EP_NONE, false, 2, false><<<E / 4, 256, 0, stream>>>(
                hfd, nullptr, 0, nullptr, 0, t1, d_n1g, g_o, d_n1b, g_o,
                d_f2w, fw_o, d_f2b, fb_o, u, E, E, E, 0, flag);
        }
        // fc1: hfd = relu( LN2_l3(u) @ fc1^T + b )
        sgemm2_k<EP_RELU, true, 0, false><<<E / 4, 256, 0, stream>>>(
            u, d_n2g, (size_t)3 * E, d_n2b, (size_t)3 * E,
            nullptr, nullptr, 0, nullptr, 0,
            fc1_w, 0, fc1_b, 0, hfd, E, E, E, 0, flag);
        // fc2 -> out slice t
        sgemm2_k<EP_NONE, false, 0, true><<<NC / 4, 256, 0, stream>>>(
            hfd, nullptr, 0, nullptr, 0, nullptr, nullptr, 0, nullptr, 0,
            fc2_w, 0, fc2_b, 0, d_out, NC, E, TOUT * NC, t * NC, flag);
    }
}